// Round 13
// baseline (361.375 us; speedup 1.0000x reference)
//
#include <hip/hip_runtime.h>
#include <math.h>

#define B_  4096
#define C_  1000
#define P_  10
#define D_  256
#define N_  10000
#define E_  160000

typedef __attribute__((ext_vector_type(8))) short short8;
typedef __attribute__((ext_vector_type(4))) float floatx4;

#define MFMA16(a, b, c) __builtin_amdgcn_mfma_f32_16x16x32_bf16((a), (b), (c), 0, 0, 0)

// ---------------- helpers ----------------
__device__ __forceinline__ float waveReduceSum(float v){
  #pragma unroll
  for (int o = 32; o > 0; o >>= 1) v += __shfl_xor(v, o);
  return v;
}
__device__ __forceinline__ unsigned short f2bf(float f){
  unsigned int u = __float_as_uint(f);
  unsigned int r = (u + 0x7FFFu + ((u >> 16) & 1u)) >> 16;
  return (unsigned short)r;
}
__device__ __forceinline__ float bf2f(unsigned short b){
  return __uint_as_float(((unsigned int)b) << 16);
}
// DMA 16B/lane global->LDS (dest = wave-uniform base + lane*16)
__device__ __forceinline__ void gload_lds16(const void* g, void* l){
  __builtin_amdgcn_global_load_lds((const __attribute__((address_space(1))) void*)g,
                                   (__attribute__((address_space(3))) void*)l, 16, 0, 0);
}
// split 8 consecutive fp32 -> bf16 hi/lo fragments (in-register)
__device__ __forceinline__ void split8(const float* __restrict__ p, short8& h8, short8& l8){
  float4 v0 = *(const float4*)p;
  float4 v1 = *(const float4*)(p + 4);
  float v[8] = {v0.x, v0.y, v0.z, v0.w, v1.x, v1.y, v1.z, v1.w};
  #pragma unroll
  for (int j = 0; j < 8; ++j){
    unsigned short h = f2bf(v[j]);
    h8[j] = (short)h;
    l8[j] = (short)f2bf(v[j] - bf2f(h));
  }
}

// ---------------- prep: scatter + W split/transpose + zero loss zone ----------
// blocks [0,625): edge scatter (cursor ends as degree)
// blocks [625,1137): W1/W2 split+transpose
// blocks [1137,1216): zero loss_out + usage arrays (20001 floats)
__global__ void k_prep(const int* __restrict__ src, const int* __restrict__ dst,
                       int* __restrict__ cursor, int* __restrict__ csr_src,
                       const float* __restrict__ w1, const float* __restrict__ w2,
                       unsigned short* __restrict__ w1h, unsigned short* __restrict__ w1l,
                       unsigned short* __restrict__ w2h, unsigned short* __restrict__ w2l,
                       float* __restrict__ zero_zone){
  int b = blockIdx.x;
  if (b < 625){
    int e = b * 256 + threadIdx.x;
    if (e < E_){
      int d = dst[e];
      int p = atomicAdd(&cursor[d], 1);
      p = (p < 63) ? p : 63;
      csr_src[d * 64 + p] = src[e];
    }
  } else if (b < 1137){
    int bb = b - 625;                 // 0..511
    int k = threadIdx.x;
    const float* w = (bb < 256) ? w1 : w2;
    int n = bb & 255;
    float x = w[(size_t)k * 256 + n];
    unsigned short h = f2bf(x);
    unsigned short l = f2bf(x - bf2f(h));
    if (bb < 256){ w1h[(size_t)n * 256 + k] = h; w1l[(size_t)n * 256 + k] = l; }
    else         { w2h[(size_t)n * 256 + k] = h; w2l[(size_t)n * 256 + k] = l; }
  } else {
    int i = (b - 1137) * 256 + threadIdx.x;
    if (i < 1 + 2 * N_) zero_zone[i] = 0.f;
  }
}

// ---------------- MFMA GEMM: out[M,256] = A_f32[M,256] @ W[256,256] (3-term split)
__global__ __launch_bounds__(64) void k_gemm_mfma(
    const float* __restrict__ A,
    const unsigned short* __restrict__ Wh, const unsigned short* __restrict__ Wl,
    float* __restrict__ outp){
  int lane = threadIdx.x;
  int l15 = lane & 15, lq = lane >> 4;
  int rb = blockIdx.x * 64;
  int nb = blockIdx.y * 32;

  floatx4 acc[4][2];
  #pragma unroll
  for (int mt = 0; mt < 4; ++mt)
    #pragma unroll
    for (int nt = 0; nt < 2; ++nt) acc[mt][nt] = (floatx4){0.f,0.f,0.f,0.f};

  int arow[4];
  #pragma unroll
  for (int mt = 0; mt < 4; ++mt){
    int r = rb + mt * 16 + l15;
    arow[mt] = (r < N_) ? r : (N_ - 1);
  }
  for (int kc = 0; kc < 256; kc += 32){
    short8 ah[4], al[4], bh[2], bl[2];
    #pragma unroll
    for (int mt = 0; mt < 4; ++mt)
      split8(A + (size_t)arow[mt] * 256 + kc + lq * 8, ah[mt], al[mt]);
    #pragma unroll
    for (int nt = 0; nt < 2; ++nt){
      size_t o = (size_t)(nb + nt * 16 + l15) * 256 + kc + lq * 8;
      bh[nt] = *(const short8*)(Wh + o);
      bl[nt] = *(const short8*)(Wl + o);
    }
    #pragma unroll
    for (int nt = 0; nt < 2; ++nt)
      #pragma unroll
      for (int mt = 0; mt < 4; ++mt) acc[mt][nt] = MFMA16(al[mt], bh[nt], acc[mt][nt]);
    #pragma unroll
    for (int nt = 0; nt < 2; ++nt)
      #pragma unroll
      for (int mt = 0; mt < 4; ++mt) acc[mt][nt] = MFMA16(ah[mt], bl[nt], acc[mt][nt]);
    #pragma unroll
    for (int nt = 0; nt < 2; ++nt)
      #pragma unroll
      for (int mt = 0; mt < 4; ++mt) acc[mt][nt] = MFMA16(ah[mt], bh[nt], acc[mt][nt]);
  }
  #pragma unroll
  for (int mt = 0; mt < 4; ++mt)
    #pragma unroll
    for (int r = 0; r < 4; ++r){
      int row = rb + mt * 16 + lq * 4 + r;
      if (row < N_){
        #pragma unroll
        for (int nt = 0; nt < 2; ++nt)
          outp[(size_t)row * 256 + nb + nt * 16 + l15] = acc[mt][nt][r];
      }
    }
}

// ---------------- GCN agg + bias + relu -> fp32 (layer 1), isq inline ----------
__global__ void k_agg_relu(const float* __restrict__ XW, const int* __restrict__ deg,
                           const int* __restrict__ csr_src,
                           const float* __restrict__ bias, float* __restrict__ X1){
  int n    = blockIdx.x * 4 + (threadIdx.x >> 6);
  int lane = threadIdx.x & 63;
  int c4   = lane * 4;
  int dgn = deg[n];
  int dg = (dgn < 64) ? dgn : 64;
  int   esr = (lane < dg) ? csr_src[n * 64 + lane] : 0;   // clamp: used as address
  float is  = 1.0f / sqrtf((float)(dgn + 1));
  float en  = (1.0f / sqrtf((float)(deg[esr] + 1))) * is;
  float4 s = *(const float4*)(XW + (size_t)n * 256 + c4);
  float w = is * is;
  float4 a = make_float4(w * s.x, w * s.y, w * s.z, w * s.w);
  int i = 0;
  for (; i + 3 < dg; i += 4){
    int s0 = __shfl(esr, i),   s1 = __shfl(esr, i+1), s2 = __shfl(esr, i+2), s3 = __shfl(esr, i+3);
    float n0 = __shfl(en, i),  n1 = __shfl(en, i+1),  n2 = __shfl(en, i+2),  n3 = __shfl(en, i+3);
    float4 v0 = *(const float4*)(XW + (size_t)s0 * 256 + c4);
    float4 v1 = *(const float4*)(XW + (size_t)s1 * 256 + c4);
    float4 v2 = *(const float4*)(XW + (size_t)s2 * 256 + c4);
    float4 v3 = *(const float4*)(XW + (size_t)s3 * 256 + c4);
    a.x += n0*v0.x + n1*v1.x + n2*v2.x + n3*v3.x;
    a.y += n0*v0.y + n1*v1.y + n2*v2.y + n3*v3.y;
    a.z += n0*v0.z + n1*v1.z + n2*v2.z + n3*v3.z;
    a.w += n0*v0.w + n1*v1.w + n2*v2.w + n3*v3.w;
  }
  for (; i < dg; ++i){
    int s0 = __shfl(esr, i); float n0 = __shfl(en, i);
    float4 v0 = *(const float4*)(XW + (size_t)s0 * 256 + c4);
    a.x += n0 * v0.x; a.y += n0 * v0.y; a.z += n0 * v0.z; a.w += n0 * v0.w;
  }
  float4 b = *(const float4*)(bias + c4);
  float4 o;
  o.x = fmaxf(a.x + b.x, 0.f); o.y = fmaxf(a.y + b.y, 0.f);
  o.z = fmaxf(a.z + b.z, 0.f); o.w = fmaxf(a.w + b.w, 0.f);
  *(float4*)(X1 + (size_t)n * 256 + c4) = o;
}

// ---------------- GCN agg + bias + relu + L2 normalize -> bf16 split (layer 2) --
__global__ void k_agg_norm_split(const float* __restrict__ XW, const int* __restrict__ deg,
                                 const int* __restrict__ csr_src,
                                 const float* __restrict__ bias,
                                 unsigned short* __restrict__ Ph, unsigned short* __restrict__ Pl){
  int n    = blockIdx.x * 4 + (threadIdx.x >> 6);
  int lane = threadIdx.x & 63;
  int c4   = lane * 4;
  int dgn = deg[n];
  int dg = (dgn < 64) ? dgn : 64;
  int   esr = (lane < dg) ? csr_src[n * 64 + lane] : 0;
  float is  = 1.0f / sqrtf((float)(dgn + 1));
  float en  = (1.0f / sqrtf((float)(deg[esr] + 1))) * is;
  float4 s = *(const float4*)(XW + (size_t)n * 256 + c4);
  float w = is * is;
  float4 a = make_float4(w * s.x, w * s.y, w * s.z, w * s.w);
  int i = 0;
  for (; i + 3 < dg; i += 4){
    int s0 = __shfl(esr, i),   s1 = __shfl(esr, i+1), s2 = __shfl(esr, i+2), s3 = __shfl(esr, i+3);
    float n0 = __shfl(en, i),  n1 = __shfl(en, i+1),  n2 = __shfl(en, i+2),  n3 = __shfl(en, i+3);
    float4 v0 = *(const float4*)(XW + (size_t)s0 * 256 + c4);
    float4 v1 = *(const float4*)(XW + (size_t)s1 * 256 + c4);
    float4 v2 = *(const float4*)(XW + (size_t)s2 * 256 + c4);
    float4 v3 = *(const float4*)(XW + (size_t)s3 * 256 + c4);
    a.x += n0*v0.x + n1*v1.x + n2*v2.x + n3*v3.x;
    a.y += n0*v0.y + n1*v1.y + n2*v2.y + n3*v3.y;
    a.z += n0*v0.z + n1*v1.z + n2*v2.z + n3*v3.z;
    a.w += n0*v0.w + n1*v1.w + n2*v2.w + n3*v3.w;
  }
  for (; i < dg; ++i){
    int s0 = __shfl(esr, i); float n0 = __shfl(en, i);
    float4 v0 = *(const float4*)(XW + (size_t)s0 * 256 + c4);
    a.x += n0 * v0.x; a.y += n0 * v0.y; a.z += n0 * v0.z; a.w += n0 * v0.w;
  }
  float4 b = *(const float4*)(bias + c4);
  float x0 = fmaxf(a.x + b.x, 0.f), x1 = fmaxf(a.y + b.y, 0.f);
  float x2 = fmaxf(a.z + b.z, 0.f), x3 = fmaxf(a.w + b.w, 0.f);
  float ss = x0*x0 + x1*x1 + x2*x2 + x3*x3;
  float tot = waveReduceSum(ss);
  float nrm = fmaxf(sqrtf(tot), 1e-12f);
  x0 /= nrm; x1 /= nrm; x2 /= nrm; x3 /= nrm;
  unsigned short h0 = f2bf(x0), h1 = f2bf(x1), h2 = f2bf(x2), h3 = f2bf(x3);
  ushort4 hv = make_ushort4(h0, h1, h2, h3);
  ushort4 lv = make_ushort4(f2bf(x0 - bf2f(h0)), f2bf(x1 - bf2f(h1)),
                            f2bf(x2 - bf2f(h2)), f2bf(x3 - bf2f(h3)));
  *(ushort4*)(Ph + (size_t)n * 256 + c4) = hv;
  *(ushort4*)(Pl + (size_t)n * 256 + c4) = lv;
}

// ---------------- hidden L2-normalize+split; tail blocks do proto colsum -------
__global__ void k_norm_split(const float* __restrict__ in,
                             unsigned short* __restrict__ hi,
                             unsigned short* __restrict__ lo,
                             const unsigned short* __restrict__ Ph,
                             const unsigned short* __restrict__ Pl,
                             float* __restrict__ svec){
  int r = blockIdx.x, t = threadIdx.x;
  if (r < B_){
    float v = in[(size_t)r * 256 + t];
    float ss = waveReduceSum(v * v);
    __shared__ float red[4];
    int w = t >> 6;
    if ((t & 63) == 0) red[w] = ss;
    __syncthreads();
    float tot = red[0] + red[1] + red[2] + red[3];
    float nrm = fmaxf(sqrtf(tot), 1e-12f);
    float x = v / nrm;
    unsigned short h = f2bf(x);
    unsigned short l = f2bf(x - bf2f(h));
    hi[(size_t)r * 256 + t] = h;
    lo[(size_t)r * 256 + t] = l;
  } else {
    int r0 = (r - B_) * 100;
    float acc = 0.f;
    for (int rr = r0; rr < r0 + 100; ++rr)
      acc += bf2f(Ph[(size_t)rr * 256 + t]) + bf2f(Pl[(size_t)rr * 256 + t]);
    atomicAdd(&svec[t], acc);
  }
}

// ---------------- MFMA sim GEMM (3-term bf16 split) + per-class max ------------
// block: 4 waves, 128 A-rows x 80 protos; wave tile 32x80 (acc[2][5]=40 AGPRs).
// B staged via global_load_lds DMA (no VGPR round-trip) into unpadded 64B rows;
// XOR-swizzled b128 reads (2-way = free). Double-buffered; barrier after MFMAs.
// Chain-paired MFMA order. (256,5): measured unified need = 100 (60 arch + 40
// acc, R12) <= 512/5 = 102 -> expect no spill, 5 blocks/CU. Tripwire: WRITE_SIZE.
__global__ __launch_bounds__(256, 5) void k_sim_max(
    const unsigned short* __restrict__ HNh, const unsigned short* __restrict__ HNl,
    const unsigned short* __restrict__ PNh, const unsigned short* __restrict__ PNl,
    float* __restrict__ out, unsigned char* __restrict__ idxb){
  // B dbuf: 2 x (hi 5120B + lo 5120B) = 20480 | epilogue 4 x 5184 = 20736
  __shared__ __align__(16) char smem[20736];

  int tid  = threadIdx.x;
  int wid  = tid >> 6;
  int lane = tid & 63;
  int l15  = lane & 15, lq = lane >> 4;
  int rbw  = blockIdx.y * 128 + wid * 32;
  int cb80 = blockIdx.x * 80;

  int swz  = (l15 >> 1) & 3;                      // reader granule xor
  int srow = lane >> 2;                           // stager: row within 16-row slice
  int skq  = (lane & 3) ^ ((lane >> 3) & 3);      // stager: logical k-quarter for its slot

  floatx4 acc[2][5];
  #pragma unroll
  for (int mt = 0; mt < 2; ++mt)
    #pragma unroll
    for (int nt = 0; nt < 5; ++nt) acc[mt][nt] = (floatx4){0.f,0.f,0.f,0.f};

  const unsigned short* a0h = HNh + (size_t)(rbw + l15) * 256 + lq * 8;
  const unsigned short* a0l = HNl + (size_t)(rbw + l15) * 256 + lq * 8;

  // one DMA call: slice c (0..4 = hi rows 16c.., 5..9 = lo rows 16(c-5)..)
  auto stage1 = [&](int kc, int pb, int c){
    int bsel = (c >= 5) ? 1 : 0;
    int s = c - bsel * 5;
    int row = s * 16 + srow;
    const unsigned short* gp = (bsel ? PNl : PNh)
        + (size_t)(cb80 + row) * 256 + kc + skq * 8;
    char* lp = smem + pb * 10240 + bsel * 5120 + s * 1024;
    gload_lds16(gp, lp);
  };
  auto stageAll = [&](int kc, int pb){
    stage1(kc, pb, wid);
    stage1(kc, pb, wid + 4);
    if (wid < 2) stage1(kc, pb, wid + 8);
  };

  // prologue: chunk 0
  stageAll(0, 0);
  short8 ah[2], al[2];
  #pragma unroll
  for (int mt = 0; mt < 2; ++mt){
    ah[mt] = *(const short8*)(a0h + (size_t)mt * 4096);
    al[mt] = *(const short8*)(a0l + (size_t)mt * 4096);
  }
  __syncthreads();

  int p = 0;
  for (int kc = 0; kc < 256; kc += 32){
    const unsigned short* Bh = (const unsigned short*)(smem + p * 10240);
    const unsigned short* Bl = Bh + 2560;
    short8 ah2[2], al2[2];
    if (kc < 224){
      stageAll(kc + 32, p ^ 1);                 // DMA: drains at the barrier, after MFMAs
      #pragma unroll
      for (int mt = 0; mt < 2; ++mt){
        ah2[mt] = *(const short8*)(a0h + (size_t)mt * 4096 + kc + 32);
        al2[mt] = *(const short8*)(a0l + (size_t)mt * 4096 + kc + 32);
      }
    }
    // nt pairs: 4 independent chains, dep distance 4 MFMAs
    #pragma unroll
    for (int nt2 = 0; nt2 < 4; nt2 += 2){
      int ro0 = ((nt2    ) * 16 + l15) * 32 + (lq ^ swz) * 8;
      int ro1 = ((nt2 + 1) * 16 + l15) * 32 + (lq ^ swz) * 8;
      short8 bh0 = *(const short8*)(Bh + ro0), bl0 = *(const short8*)(Bl + ro0);
      short8 bh1 = *(const short8*)(Bh + ro1), bl1 = *(const short8*)(Bl + ro1);
      acc[0][nt2]   = MFMA16(al[0], bh0, acc[0][nt2]);
      acc[1][nt2]   = MFMA16(al[1], bh0, acc[1][nt2]);
      acc[0][nt2+1] = MFMA16(al[0], bh1, acc[0][nt2+1]);
      acc[1][nt2+1] = MFMA16(al[1], bh1, acc[1][nt2+1]);
      acc[0][nt2]   = MFMA16(ah[0], bl0, acc[0][nt2]);
      acc[1][nt2]   = MFMA16(ah[1], bl0, acc[1][nt2]);
      acc[0][nt2+1] = MFMA16(ah[0], bl1, acc[0][nt2+1]);
      acc[1][nt2+1] = MFMA16(ah[1], bl1, acc[1][nt2+1]);
      acc[0][nt2]   = MFMA16(ah[0], bh0, acc[0][nt2]);
      acc[1][nt2]   = MFMA16(ah[1], bh0, acc[1][nt2]);
      acc[0][nt2+1] = MFMA16(ah[0], bh1, acc[0][nt2+1]);
      acc[1][nt2+1] = MFMA16(ah[1], bh1, acc[1][nt2+1]);
    }
    {   // nt = 4 tail: 2 chains
      int ro = (4 * 16 + l15) * 32 + (lq ^ swz) * 8;
      short8 bh = *(const short8*)(Bh + ro), bl = *(const short8*)(Bl + ro);
      acc[0][4] = MFMA16(al[0], bh, acc[0][4]);
      acc[1][4] = MFMA16(al[1], bh, acc[1][4]);
      acc[0][4] = MFMA16(ah[0], bl, acc[0][4]);
      acc[1][4] = MFMA16(ah[1], bl, acc[1][4]);
      acc[0][4] = MFMA16(ah[0], bh, acc[0][4]);
      acc[1][4] = MFMA16(ah[1], bh, acc[1][4]);
    }
    ah[0] = ah2[0]; ah[1] = ah2[1];
    al[0] = al2[0]; al[1] = al2[1];
    __syncthreads();                          // single drain point, after MFMAs
    p ^= 1;
  }

  // epilogue: per-wave 16x81 scratch overlaying the (dead) B buffers.
  float* redw = (float*)smem + wid * 1296;
  #pragma unroll
  for (int mt = 0; mt < 2; ++mt){
    #pragma unroll
    for (int nt = 0; nt < 5; ++nt)
      #pragma unroll
      for (int r = 0; r < 4; ++r)
        redw[(lq * 4 + r) * 81 + nt * 16 + l15] = acc[mt][nt][r];
    int row = lane >> 2;      // 0..15
    int q   = lane & 3;       // 0..3 -> 2 classes each
    const float* basep = redw + row * 81 + q * 20;
    float vs[2]; int is[2];
    #pragma unroll
    for (int cc = 0; cc < 2; ++cc){
      float m = 0.5f * (1.0f + basep[cc * 10]); int mi = 0;
      #pragma unroll
      for (int p2 = 1; p2 < 10; ++p2){
        float v = 0.5f * (1.0f + basep[cc * 10 + p2]);
        if (v > m){ m = v; mi = p2; }
      }
      vs[cc] = m; is[cc] = mi;
    }
    int grow = rbw + mt * 16 + row;
    int gcol = blockIdx.x * 8 + q * 2;
    *(float2*)(out + (size_t)grow * 1000 + gcol) = make_float2(vs[0], vs[1]);
    idxb[(size_t)grow * 1000 + gcol]     = (unsigned char)is[0];
    idxb[(size_t)grow * 1000 + gcol + 1] = (unsigned char)is[1];
  }
}

// ---------------- per-sample pass: softmax CE + mask + usage ----------------
__global__ void k_row_pass(const float* __restrict__ out, const unsigned char* __restrict__ idxb,
                           const int* __restrict__ labels, int* __restrict__ cnt,
                           float* __restrict__ ce_sum, float* __restrict__ pos_usage,
                           float* __restrict__ neg_usage){
  int b = blockIdx.x * 4 + (threadIdx.x >> 6);
  int lane = threadIdx.x & 63;
  const float* row = out + (size_t)b * 1000;
  float m = -INFINITY, s = 0.f; int bi = 0x7fffffff;
  for (int c = lane; c < 1000; c += 64){
    float v = row[c];
    if (v > m){ s = s * expf(m - v) + 1.f; bi = c; m = v; }
    else       s += expf(v - m);
  }
  #pragma unroll
  for (int o = 32; o > 0; o >>= 1){
    float m2 = __shfl_xor(m, o);
    float s2 = __shfl_xor(s, o);
    int   b2 = __shfl_xor(bi, o);
    float M = fmaxf(m, m2);
    s = s * expf(m - M) + s2 * expf(m2 - M);
    if (m2 > m || (m2 == m && b2 < bi)) bi = b2;
    m = M;
  }
  if (lane == 0){
    int lab = labels[b];
    float true_score = row[lab];
    float per_ce = m + logf(s) - true_score;
    bool mask = (true_score - m) > -0.1f;
    if (mask){ atomicAdd(cnt, 1); atomicAdd(ce_sum, per_ce); }
    int pi = idxb[(size_t)b * 1000 + lab];
    atomicAdd(&pos_usage[lab * P_ + pi], 1.f);
    if (bi != lab){
      int ni = idxb[(size_t)b * 1000 + bi];
      atomicAdd(&neg_usage[bi * P_ + ni], 1.f);
    }
  }
}

// ---------------- finalize loss ----------------
__global__ void k_finalize(const float* __restrict__ s, const int* __restrict__ cnt,
                           const float* __restrict__ ce_sum, float* __restrict__ loss_out){
  int t = threadIdx.x;
  float v = s[t];
  float ss = waveReduceSum(v * v);
  __shared__ float red[4];
  if ((t & 63) == 0) red[t >> 6] = ss;
  __syncthreads();
  if (t == 0){
    float tot = red[0] + red[1] + red[2] + red[3];
    float disp = -tot / 1.0e8f;
    int c = *cnt;
    float total = (c == 0) ? 0.f
                : (*ce_sum / (float)(c < 1 ? 1 : c) + 0.1f * disp);
    *loss_out = total;
  }
}

// ---------------- launcher ----------------
extern "C" void kernel_launch(void* const* d_in, const int* in_sizes, int n_in,
                              void* d_out, int out_size, void* d_ws, size_t ws_size,
                              hipStream_t stream){
  const float* hidden = (const float*)d_in[0];
  const int*   labels = (const int*)  d_in[1];
  const int*   eidx   = (const int*)  d_in[2];
  const float* nodef  = (const float*)d_in[3];
  const float* w1     = (const float*)d_in[4];
  const float* b1     = (const float*)d_in[5];
  const float* w2     = (const float*)d_in[6];
  const float* b2     = (const float*)d_in[7];

  float* out       = (float*)d_out;
  float* loss_out  = out + (size_t)B_ * C_;
  float* pos_usage = loss_out + 1;
  float* neg_usage = pos_usage + N_;

  const int* srcp = eidx;
  const int* dstp = eidx + E_;

  char* base = (char*)d_ws;
  size_t off = 0;
  auto alloc = [&](size_t bytes) -> char* {
    char* p = base + off;
    off = (off + bytes + 255) & ~(size_t)255;
    return p;
  };
  // zero zone: cursor (ends as degree), svec, cnt, ce_sum (one memset)
  int*   cursor  = (int*)  alloc((size_t)N_ * 4);
  float* svec    = (float*)alloc(256 * 4);
  int*   cnt     = (int*)  alloc(4);
  float* ce_sum  = (float*)alloc(4);
  size_t zero_bytes = off;
  int*   csr_src   = (int*)  alloc((size_t)N_ * 64 * 4);
  float* XW        = (float*)alloc((size_t)N_ * 256 * 4);   // gemm output (both layers)
  float* X1        = (float*)alloc((size_t)N_ * 256 * 4);   // layer-1 activations fp32
  unsigned short* Ph  = (unsigned short*)alloc((size_t)N_ * 256 * 2);
  unsigned short* Pl  = (unsigned short*)alloc((size_t)N_ * 256 * 2);
  unsigned short* W1h = (unsigned short*)alloc(256 * 256 * 2);
  unsigned short* W1l = (unsigned short*)alloc(256 * 256 * 2);
  unsigned short* W2h = (unsigned short*)alloc(256 * 256 * 2);
  unsigned short* W2l = (unsigned short*)alloc(256 * 256 * 2);
  unsigned short* HNh = (unsigned short*)alloc((size_t)B_ * 256 * 2);
  unsigned short* HNl = (unsigned short*)alloc((size_t)B_ * 256 * 2);
  unsigned char* idxb = (unsigned char*)alloc((size_t)B_ * C_);

  hipMemsetAsync(base, 0, zero_bytes, stream);

  // prep: scatter (625) + W split (512) + zero loss/usage (79)
  k_prep<<<1216, 256, 0, stream>>>(srcp, dstp, cursor, csr_src,
                                   w1, w2, W1h, W1l, W2h, W2l, loss_out);

  dim3 ggrid(157, 8);
  k_gemm_mfma<<<ggrid, 64, 0, stream>>>(nodef, W1h, W1l, XW);
  k_agg_relu<<<N_ / 4, 256, 0, stream>>>(XW, cursor, csr_src, b1, X1);
  k_gemm_mfma<<<ggrid, 64, 0, stream>>>(X1, W2h, W2l, XW);
  k_agg_norm_split<<<N_ / 4, 256, 0, stream>>>(XW, cursor, csr_src, b2, Ph, Pl);

  // hidden normalize+split (4096 blocks) + proto colsum (100 tail blocks)
  k_norm_split<<<B_ + 100, 256, 0, stream>>>(hidden, HNh, HNl, Ph, Pl, svec);

  dim3 sgrid(125, 32);
  k_sim_max<<<sgrid, 256, 0, stream>>>(HNh, HNl, Ph, Pl, out, idxb);

  k_row_pass<<<B_ / 4, 256, 0, stream>>>(out, idxb, labels, cnt, ce_sum, pos_usage, neg_usage);
  k_finalize<<<1, 256, 0, stream>>>(svec, cnt, ce_sum, loss_out);
}

// Round 14
// 340.812 us; speedup vs baseline: 1.0603x; 1.0603x over previous
//
#include <hip/hip_runtime.h>
#include <math.h>

#define B_  4096
#define C_  1000
#define P_  10
#define D_  256
#define N_  10000
#define E_  160000

typedef __attribute__((ext_vector_type(8))) short short8;
typedef __attribute__((ext_vector_type(4))) float floatx4;

#define MFMA16(a, b, c) __builtin_amdgcn_mfma_f32_16x16x32_bf16((a), (b), (c), 0, 0, 0)

// ---------------- helpers ----------------
__device__ __forceinline__ float waveReduceSum(float v){
  #pragma unroll
  for (int o = 32; o > 0; o >>= 1) v += __shfl_xor(v, o);
  return v;
}
__device__ __forceinline__ unsigned short f2bf(float f){
  unsigned int u = __float_as_uint(f);
  unsigned int r = (u + 0x7FFFu + ((u >> 16) & 1u)) >> 16;
  return (unsigned short)r;
}
__device__ __forceinline__ float bf2f(unsigned short b){
  return __uint_as_float(((unsigned int)b) << 16);
}
// DMA 16B/lane global->LDS (dest = wave-uniform base + lane*16)
__device__ __forceinline__ void gload_lds16(const void* g, void* l){
  __builtin_amdgcn_global_load_lds((const __attribute__((address_space(1))) void*)g,
                                   (__attribute__((address_space(3))) void*)l, 16, 0, 0);
}
// split 8 consecutive fp32 -> bf16 hi/lo fragments (in-register)
__device__ __forceinline__ void split8(const float* __restrict__ p, short8& h8, short8& l8){
  float4 v0 = *(const float4*)p;
  float4 v1 = *(const float4*)(p + 4);
  float v[8] = {v0.x, v0.y, v0.z, v0.w, v1.x, v1.y, v1.z, v1.w};
  #pragma unroll
  for (int j = 0; j < 8; ++j){
    unsigned short h = f2bf(v[j]);
    h8[j] = (short)h;
    l8[j] = (short)f2bf(v[j] - bf2f(h));
  }
}

// ---------------- prep: scatter + W split/transpose + zero loss zone ----------
__global__ void k_prep(const int* __restrict__ src, const int* __restrict__ dst,
                       int* __restrict__ cursor, int* __restrict__ csr_src,
                       const float* __restrict__ w1, const float* __restrict__ w2,
                       unsigned short* __restrict__ w1h, unsigned short* __restrict__ w1l,
                       unsigned short* __restrict__ w2h, unsigned short* __restrict__ w2l,
                       float* __restrict__ zero_zone){
  int b = blockIdx.x;
  if (b < 625){
    int e = b * 256 + threadIdx.x;
    if (e < E_){
      int d = dst[e];
      int p = atomicAdd(&cursor[d], 1);
      p = (p < 63) ? p : 63;
      csr_src[d * 64 + p] = src[e];
    }
  } else if (b < 1137){
    int bb = b - 625;                 // 0..511
    int k = threadIdx.x;
    const float* w = (bb < 256) ? w1 : w2;
    int n = bb & 255;
    float x = w[(size_t)k * 256 + n];
    unsigned short h = f2bf(x);
    unsigned short l = f2bf(x - bf2f(h));
    if (bb < 256){ w1h[(size_t)n * 256 + k] = h; w1l[(size_t)n * 256 + k] = l; }
    else         { w2h[(size_t)n * 256 + k] = h; w2l[(size_t)n * 256 + k] = l; }
  } else {
    int i = (b - 1137) * 256 + threadIdx.x;
    if (i < 1 + 2 * N_) zero_zone[i] = 0.f;
  }
}

// ---------------- MFMA GEMM: out[M,256] = A_f32[M,256] @ W[256,256] (3-term split)
__global__ __launch_bounds__(64) void k_gemm_mfma(
    const float* __restrict__ A,
    const unsigned short* __restrict__ Wh, const unsigned short* __restrict__ Wl,
    float* __restrict__ outp){
  int lane = threadIdx.x;
  int l15 = lane & 15, lq = lane >> 4;
  int rb = blockIdx.x * 64;
  int nb = blockIdx.y * 32;

  floatx4 acc[4][2];
  #pragma unroll
  for (int mt = 0; mt < 4; ++mt)
    #pragma unroll
    for (int nt = 0; nt < 2; ++nt) acc[mt][nt] = (floatx4){0.f,0.f,0.f,0.f};

  int arow[4];
  #pragma unroll
  for (int mt = 0; mt < 4; ++mt){
    int r = rb + mt * 16 + l15;
    arow[mt] = (r < N_) ? r : (N_ - 1);
  }
  for (int kc = 0; kc < 256; kc += 32){
    short8 ah[4], al[4], bh[2], bl[2];
    #pragma unroll
    for (int mt = 0; mt < 4; ++mt)
      split8(A + (size_t)arow[mt] * 256 + kc + lq * 8, ah[mt], al[mt]);
    #pragma unroll
    for (int nt = 0; nt < 2; ++nt){
      size_t o = (size_t)(nb + nt * 16 + l15) * 256 + kc + lq * 8;
      bh[nt] = *(const short8*)(Wh + o);
      bl[nt] = *(const short8*)(Wl + o);
    }
    #pragma unroll
    for (int nt = 0; nt < 2; ++nt)
      #pragma unroll
      for (int mt = 0; mt < 4; ++mt) acc[mt][nt] = MFMA16(al[mt], bh[nt], acc[mt][nt]);
    #pragma unroll
    for (int nt = 0; nt < 2; ++nt)
      #pragma unroll
      for (int mt = 0; mt < 4; ++mt) acc[mt][nt] = MFMA16(ah[mt], bl[nt], acc[mt][nt]);
    #pragma unroll
    for (int nt = 0; nt < 2; ++nt)
      #pragma unroll
      for (int mt = 0; mt < 4; ++mt) acc[mt][nt] = MFMA16(ah[mt], bh[nt], acc[mt][nt]);
  }
  #pragma unroll
  for (int mt = 0; mt < 4; ++mt)
    #pragma unroll
    for (int r = 0; r < 4; ++r){
      int row = rb + mt * 16 + lq * 4 + r;
      if (row < N_){
        #pragma unroll
        for (int nt = 0; nt < 2; ++nt)
          outp[(size_t)row * 256 + nb + nt * 16 + l15] = acc[mt][nt][r];
      }
    }
}

// ---------------- GCN agg + bias + relu -> fp32 (layer 1), isq inline ----------
__global__ void k_agg_relu(const float* __restrict__ XW, const int* __restrict__ deg,
                           const int* __restrict__ csr_src,
                           const float* __restrict__ bias, float* __restrict__ X1){
  int n    = blockIdx.x * 4 + (threadIdx.x >> 6);
  int lane = threadIdx.x & 63;
  int c4   = lane * 4;
  int dgn = deg[n];
  int dg = (dgn < 64) ? dgn : 64;
  int   esr = (lane < dg) ? csr_src[n * 64 + lane] : 0;   // clamp: used as address
  float is  = 1.0f / sqrtf((float)(dgn + 1));
  float en  = (1.0f / sqrtf((float)(deg[esr] + 1))) * is;
  float4 s = *(const float4*)(XW + (size_t)n * 256 + c4);
  float w = is * is;
  float4 a = make_float4(w * s.x, w * s.y, w * s.z, w * s.w);
  int i = 0;
  for (; i + 3 < dg; i += 4){
    int s0 = __shfl(esr, i),   s1 = __shfl(esr, i+1), s2 = __shfl(esr, i+2), s3 = __shfl(esr, i+3);
    float n0 = __shfl(en, i),  n1 = __shfl(en, i+1),  n2 = __shfl(en, i+2),  n3 = __shfl(en, i+3);
    float4 v0 = *(const float4*)(XW + (size_t)s0 * 256 + c4);
    float4 v1 = *(const float4*)(XW + (size_t)s1 * 256 + c4);
    float4 v2 = *(const float4*)(XW + (size_t)s2 * 256 + c4);
    float4 v3 = *(const float4*)(XW + (size_t)s3 * 256 + c4);
    a.x += n0*v0.x + n1*v1.x + n2*v2.x + n3*v3.x;
    a.y += n0*v0.y + n1*v1.y + n2*v2.y + n3*v3.y;
    a.z += n0*v0.z + n1*v1.z + n2*v2.z + n3*v3.z;
    a.w += n0*v0.w + n1*v1.w + n2*v2.w + n3*v3.w;
  }
  for (; i < dg; ++i){
    int s0 = __shfl(esr, i); float n0 = __shfl(en, i);
    float4 v0 = *(const float4*)(XW + (size_t)s0 * 256 + c4);
    a.x += n0 * v0.x; a.y += n0 * v0.y; a.z += n0 * v0.z; a.w += n0 * v0.w;
  }
  float4 b = *(const float4*)(bias + c4);
  float4 o;
  o.x = fmaxf(a.x + b.x, 0.f); o.y = fmaxf(a.y + b.y, 0.f);
  o.z = fmaxf(a.z + b.z, 0.f); o.w = fmaxf(a.w + b.w, 0.f);
  *(float4*)(X1 + (size_t)n * 256 + c4) = o;
}

// ---------------- GCN agg + bias + relu + L2 normalize -> bf16 split (layer 2) --
__global__ void k_agg_norm_split(const float* __restrict__ XW, const int* __restrict__ deg,
                                 const int* __restrict__ csr_src,
                                 const float* __restrict__ bias,
                                 unsigned short* __restrict__ Ph, unsigned short* __restrict__ Pl){
  int n    = blockIdx.x * 4 + (threadIdx.x >> 6);
  int lane = threadIdx.x & 63;
  int c4   = lane * 4;
  int dgn = deg[n];
  int dg = (dgn < 64) ? dgn : 64;
  int   esr = (lane < dg) ? csr_src[n * 64 + lane] : 0;
  float is  = 1.0f / sqrtf((float)(dgn + 1));
  float en  = (1.0f / sqrtf((float)(deg[esr] + 1))) * is;
  float4 s = *(const float4*)(XW + (size_t)n * 256 + c4);
  float w = is * is;
  float4 a = make_float4(w * s.x, w * s.y, w * s.z, w * s.w);
  int i = 0;
  for (; i + 3 < dg; i += 4){
    int s0 = __shfl(esr, i),   s1 = __shfl(esr, i+1), s2 = __shfl(esr, i+2), s3 = __shfl(esr, i+3);
    float n0 = __shfl(en, i),  n1 = __shfl(en, i+1),  n2 = __shfl(en, i+2),  n3 = __shfl(en, i+3);
    float4 v0 = *(const float4*)(XW + (size_t)s0 * 256 + c4);
    float4 v1 = *(const float4*)(XW + (size_t)s1 * 256 + c4);
    float4 v2 = *(const float4*)(XW + (size_t)s2 * 256 + c4);
    float4 v3 = *(const float4*)(XW + (size_t)s3 * 256 + c4);
    a.x += n0*v0.x + n1*v1.x + n2*v2.x + n3*v3.x;
    a.y += n0*v0.y + n1*v1.y + n2*v2.y + n3*v3.y;
    a.z += n0*v0.z + n1*v1.z + n2*v2.z + n3*v3.z;
    a.w += n0*v0.w + n1*v1.w + n2*v2.w + n3*v3.w;
  }
  for (; i < dg; ++i){
    int s0 = __shfl(esr, i); float n0 = __shfl(en, i);
    float4 v0 = *(const float4*)(XW + (size_t)s0 * 256 + c4);
    a.x += n0 * v0.x; a.y += n0 * v0.y; a.z += n0 * v0.z; a.w += n0 * v0.w;
  }
  float4 b = *(const float4*)(bias + c4);
  float x0 = fmaxf(a.x + b.x, 0.f), x1 = fmaxf(a.y + b.y, 0.f);
  float x2 = fmaxf(a.z + b.z, 0.f), x3 = fmaxf(a.w + b.w, 0.f);
  float ss = x0*x0 + x1*x1 + x2*x2 + x3*x3;
  float tot = waveReduceSum(ss);
  float nrm = fmaxf(sqrtf(tot), 1e-12f);
  x0 /= nrm; x1 /= nrm; x2 /= nrm; x3 /= nrm;
  unsigned short h0 = f2bf(x0), h1 = f2bf(x1), h2 = f2bf(x2), h3 = f2bf(x3);
  ushort4 hv = make_ushort4(h0, h1, h2, h3);
  ushort4 lv = make_ushort4(f2bf(x0 - bf2f(h0)), f2bf(x1 - bf2f(h1)),
                            f2bf(x2 - bf2f(h2)), f2bf(x3 - bf2f(h3)));
  *(ushort4*)(Ph + (size_t)n * 256 + c4) = hv;
  *(ushort4*)(Pl + (size_t)n * 256 + c4) = lv;
}

// ---------------- hidden L2-normalize+split; tail blocks do proto colsum -------
__global__ void k_norm_split(const float* __restrict__ in,
                             unsigned short* __restrict__ hi,
                             unsigned short* __restrict__ lo,
                             const unsigned short* __restrict__ Ph,
                             const unsigned short* __restrict__ Pl,
                             float* __restrict__ svec){
  int r = blockIdx.x, t = threadIdx.x;
  if (r < B_){
    float v = in[(size_t)r * 256 + t];
    float ss = waveReduceSum(v * v);
    __shared__ float red[4];
    int w = t >> 6;
    if ((t & 63) == 0) red[w] = ss;
    __syncthreads();
    float tot = red[0] + red[1] + red[2] + red[3];
    float nrm = fmaxf(sqrtf(tot), 1e-12f);
    float x = v / nrm;
    unsigned short h = f2bf(x);
    unsigned short l = f2bf(x - bf2f(h));
    hi[(size_t)r * 256 + t] = h;
    lo[(size_t)r * 256 + t] = l;
  } else {
    int r0 = (r - B_) * 100;
    float acc = 0.f;
    for (int rr = r0; rr < r0 + 100; ++rr)
      acc += bf2f(Ph[(size_t)rr * 256 + t]) + bf2f(Pl[(size_t)rr * 256 + t]);
    atomicAdd(&svec[t], acc);
  }
}

// ---------------- MFMA sim GEMM (3-term bf16 split) + per-class max ------------
// block: 4 waves, 128 A-rows x 80 protos; wave tile 32x80 (acc[2][5]=40 AGPRs).
// B staged via global_load_lds DMA into unpadded 64B rows; XOR-swizzled b128
// reads (2-way = free). Double-buffered; barrier after MFMAs. MFMA order:
// nt groups {0,1,2} then {3,4} -> dep distance 6 / 4 (all >= issue window).
// LAW (R6/R11/R13, thrice-measured): this tile NEEDS launch_bounds(256,4).
// Any tighter cap (5 waves/EU = 102 regs) spills acc -> WRITE_SIZE balloons.
__global__ __launch_bounds__(256, 4) void k_sim_max(
    const unsigned short* __restrict__ HNh, const unsigned short* __restrict__ HNl,
    const unsigned short* __restrict__ PNh, const unsigned short* __restrict__ PNl,
    float* __restrict__ out, unsigned char* __restrict__ idxb){
  // B dbuf: 2 x (hi 5120B + lo 5120B) = 20480 | epilogue 4 x 5184 = 20736
  __shared__ __align__(16) char smem[20736];

  int tid  = threadIdx.x;
  int wid  = tid >> 6;
  int lane = tid & 63;
  int l15  = lane & 15, lq = lane >> 4;
  int rbw  = blockIdx.y * 128 + wid * 32;
  int cb80 = blockIdx.x * 80;

  int swz  = (l15 >> 1) & 3;                      // reader granule xor
  int srow = lane >> 2;                           // stager: row within 16-row slice
  int skq  = (lane & 3) ^ ((lane >> 3) & 3);      // stager: logical k-quarter for its slot

  floatx4 acc[2][5];
  #pragma unroll
  for (int mt = 0; mt < 2; ++mt)
    #pragma unroll
    for (int nt = 0; nt < 5; ++nt) acc[mt][nt] = (floatx4){0.f,0.f,0.f,0.f};

  const unsigned short* a0h = HNh + (size_t)(rbw + l15) * 256 + lq * 8;
  const unsigned short* a0l = HNl + (size_t)(rbw + l15) * 256 + lq * 8;

  // one DMA call: slice c (0..4 = hi rows 16c.., 5..9 = lo rows 16(c-5)..)
  auto stage1 = [&](int kc, int pb, int c){
    int bsel = (c >= 5) ? 1 : 0;
    int s = c - bsel * 5;
    int row = s * 16 + srow;
    const unsigned short* gp = (bsel ? PNl : PNh)
        + (size_t)(cb80 + row) * 256 + kc + skq * 8;
    char* lp = smem + pb * 10240 + bsel * 5120 + s * 1024;
    gload_lds16(gp, lp);
  };
  auto stageAll = [&](int kc, int pb){
    stage1(kc, pb, wid);
    stage1(kc, pb, wid + 4);
    if (wid < 2) stage1(kc, pb, wid + 8);
  };

  // prologue: chunk 0
  stageAll(0, 0);
  short8 ah[2], al[2];
  #pragma unroll
  for (int mt = 0; mt < 2; ++mt){
    ah[mt] = *(const short8*)(a0h + (size_t)mt * 4096);
    al[mt] = *(const short8*)(a0l + (size_t)mt * 4096);
  }
  __syncthreads();

  int p = 0;
  for (int kc = 0; kc < 256; kc += 32){
    const unsigned short* Bh = (const unsigned short*)(smem + p * 10240);
    const unsigned short* Bl = Bh + 2560;
    short8 ah2[2], al2[2];
    if (kc < 224){
      stageAll(kc + 32, p ^ 1);                 // DMA: drains at the barrier, after MFMAs
      #pragma unroll
      for (int mt = 0; mt < 2; ++mt){
        ah2[mt] = *(const short8*)(a0h + (size_t)mt * 4096 + kc + 32);
        al2[mt] = *(const short8*)(a0l + (size_t)mt * 4096 + kc + 32);
      }
    }
    // group {0,1,2}: 18 MFMAs, dep distance 6
    {
      int r0 = (0 * 16 + l15) * 32 + (lq ^ swz) * 8;
      int r1 = (1 * 16 + l15) * 32 + (lq ^ swz) * 8;
      int r2 = (2 * 16 + l15) * 32 + (lq ^ swz) * 8;
      short8 bh0 = *(const short8*)(Bh + r0), bl0 = *(const short8*)(Bl + r0);
      short8 bh1 = *(const short8*)(Bh + r1), bl1 = *(const short8*)(Bl + r1);
      short8 bh2 = *(const short8*)(Bh + r2), bl2 = *(const short8*)(Bl + r2);
      acc[0][0] = MFMA16(al[0], bh0, acc[0][0]);
      acc[1][0] = MFMA16(al[1], bh0, acc[1][0]);
      acc[0][1] = MFMA16(al[0], bh1, acc[0][1]);
      acc[1][1] = MFMA16(al[1], bh1, acc[1][1]);
      acc[0][2] = MFMA16(al[0], bh2, acc[0][2]);
      acc[1][2] = MFMA16(al[1], bh2, acc[1][2]);
      acc[0][0] = MFMA16(ah[0], bl0, acc[0][0]);
      acc[1][0] = MFMA16(ah[1], bl0, acc[1][0]);
      acc[0][1] = MFMA16(ah[0], bl1, acc[0][1]);
      acc[1][1] = MFMA16(ah[1], bl1, acc[1][1]);
      acc[0][2] = MFMA16(ah[0], bl2, acc[0][2]);
      acc[1][2] = MFMA16(ah[1], bl2, acc[1][2]);
      acc[0][0] = MFMA16(ah[0], bh0, acc[0][0]);
      acc[1][0] = MFMA16(ah[1], bh0, acc[1][0]);
      acc[0][1] = MFMA16(ah[0], bh1, acc[0][1]);
      acc[1][1] = MFMA16(ah[1], bh1, acc[1][1]);
      acc[0][2] = MFMA16(ah[0], bh2, acc[0][2]);
      acc[1][2] = MFMA16(ah[1], bh2, acc[1][2]);
    }
    // group {3,4}: 12 MFMAs, dep distance 4
    {
      int r3 = (3 * 16 + l15) * 32 + (lq ^ swz) * 8;
      int r4 = (4 * 16 + l15) * 32 + (lq ^ swz) * 8;
      short8 bh3 = *(const short8*)(Bh + r3), bl3 = *(const short8*)(Bl + r3);
      short8 bh4 = *(const short8*)(Bh + r4), bl4 = *(const short8*)(Bl + r4);
      acc[0][3] = MFMA16(al[0], bh3, acc[0][3]);
      acc[1][3] = MFMA16(al[1], bh3, acc[1][3]);
      acc[0][4] = MFMA16(al[0], bh4, acc[0][4]);
      acc[1][4] = MFMA16(al[1], bh4, acc[1][4]);
      acc[0][3] = MFMA16(ah[0], bl3, acc[0][3]);
      acc[1][3] = MFMA16(ah[1], bl3, acc[1][3]);
      acc[0][4] = MFMA16(ah[0], bl4, acc[0][4]);
      acc[1][4] = MFMA16(ah[1], bl4, acc[1][4]);
      acc[0][3] = MFMA16(ah[0], bh3, acc[0][3]);
      acc[1][3] = MFMA16(ah[1], bh3, acc[1][3]);
      acc[0][4] = MFMA16(ah[0], bh4, acc[0][4]);
      acc[1][4] = MFMA16(ah[1], bh4, acc[1][4]);
    }
    ah[0] = ah2[0]; ah[1] = ah2[1];
    al[0] = al2[0]; al[1] = al2[1];
    __syncthreads();                          // single drain point, after MFMAs
    p ^= 1;
  }

  // epilogue: per-wave 16x81 scratch overlaying the (dead) B buffers.
  float* redw = (float*)smem + wid * 1296;
  #pragma unroll
  for (int mt = 0; mt < 2; ++mt){
    #pragma unroll
    for (int nt = 0; nt < 5; ++nt)
      #pragma unroll
      for (int r = 0; r < 4; ++r)
        redw[(lq * 4 + r) * 81 + nt * 16 + l15] = acc[mt][nt][r];
    int row = lane >> 2;      // 0..15
    int q   = lane & 3;       // 0..3 -> 2 classes each
    const float* basep = redw + row * 81 + q * 20;
    float vs[2]; int is[2];
    #pragma unroll
    for (int cc = 0; cc < 2; ++cc){
      float m = 0.5f * (1.0f + basep[cc * 10]); int mi = 0;
      #pragma unroll
      for (int p2 = 1; p2 < 10; ++p2){
        float v = 0.5f * (1.0f + basep[cc * 10 + p2]);
        if (v > m){ m = v; mi = p2; }
      }
      vs[cc] = m; is[cc] = mi;
    }
    int grow = rbw + mt * 16 + row;
    int gcol = blockIdx.x * 8 + q * 2;
    *(float2*)(out + (size_t)grow * 1000 + gcol) = make_float2(vs[0], vs[1]);
    idxb[(size_t)grow * 1000 + gcol]     = (unsigned char)is[0];
    idxb[(size_t)grow * 1000 + gcol + 1] = (unsigned char)is[1];
  }
}

// ---------------- per-sample pass: softmax CE + mask + usage ----------------
__global__ void k_row_pass(const float* __restrict__ out, const unsigned char* __restrict__ idxb,
                           const int* __restrict__ labels, int* __restrict__ cnt,
                           float* __restrict__ ce_sum, float* __restrict__ pos_usage,
                           float* __restrict__ neg_usage){
  int b = blockIdx.x * 4 + (threadIdx.x >> 6);
  int lane = threadIdx.x & 63;
  const float* row = out + (size_t)b * 1000;
  float m = -INFINITY, s = 0.f; int bi = 0x7fffffff;
  for (int c = lane; c < 1000; c += 64){
    float v = row[c];
    if (v > m){ s = s * expf(m - v) + 1.f; bi = c; m = v; }
    else       s += expf(v - m);
  }
  #pragma unroll
  for (int o = 32; o > 0; o >>= 1){
    float m2 = __shfl_xor(m, o);
    float s2 = __shfl_xor(s, o);
    int   b2 = __shfl_xor(bi, o);
    float M = fmaxf(m, m2);
    s = s * expf(m - M) + s2 * expf(m2 - M);
    if (m2 > m || (m2 == m && b2 < bi)) bi = b2;
    m = M;
  }
  if (lane == 0){
    int lab = labels[b];
    float true_score = row[lab];
    float per_ce = m + logf(s) - true_score;
    bool mask = (true_score - m) > -0.1f;
    if (mask){ atomicAdd(cnt, 1); atomicAdd(ce_sum, per_ce); }
    int pi = idxb[(size_t)b * 1000 + lab];
    atomicAdd(&pos_usage[lab * P_ + pi], 1.f);
    if (bi != lab){
      int ni = idxb[(size_t)b * 1000 + bi];
      atomicAdd(&neg_usage[bi * P_ + ni], 1.f);
    }
  }
}

// ---------------- finalize loss ----------------
__global__ void k_finalize(const float* __restrict__ s, const int* __restrict__ cnt,
                           const float* __restrict__ ce_sum, float* __restrict__ loss_out){
  int t = threadIdx.x;
  float v = s[t];
  float ss = waveReduceSum(v * v);
  __shared__ float red[4];
  if ((t & 63) == 0) red[t >> 6] = ss;
  __syncthreads();
  if (t == 0){
    float tot = red[0] + red[1] + red[2] + red[3];
    float disp = -tot / 1.0e8f;
    int c = *cnt;
    float total = (c == 0) ? 0.f
                : (*ce_sum / (float)(c < 1 ? 1 : c) + 0.1f * disp);
    *loss_out = total;
  }
}

// ---------------- launcher ----------------
extern "C" void kernel_launch(void* const* d_in, const int* in_sizes, int n_in,
                              void* d_out, int out_size, void* d_ws, size_t ws_size,
                              hipStream_t stream){
  const float* hidden = (const float*)d_in[0];
  const int*   labels = (const int*)  d_in[1];
  const int*   eidx   = (const int*)  d_in[2];
  const float* nodef  = (const float*)d_in[3];
  const float* w1     = (const float*)d_in[4];
  const float* b1     = (const float*)d_in[5];
  const float* w2     = (const float*)d_in[6];
  const float* b2     = (const float*)d_in[7];

  float* out       = (float*)d_out;
  float* loss_out  = out + (size_t)B_ * C_;
  float* pos_usage = loss_out + 1;
  float* neg_usage = pos_usage + N_;

  const int* srcp = eidx;
  const int* dstp = eidx + E_;

  char* base = (char*)d_ws;
  size_t off = 0;
  auto alloc = [&](size_t bytes) -> char* {
    char* p = base + off;
    off = (off + bytes + 255) & ~(size_t)255;
    return p;
  };
  // zero zone: cursor (ends as degree), svec, cnt, ce_sum (one memset)
  int*   cursor  = (int*)  alloc((size_t)N_ * 4);
  float* svec    = (float*)alloc(256 * 4);
  int*   cnt     = (int*)  alloc(4);
  float* ce_sum  = (float*)alloc(4);
  size_t zero_bytes = off;
  int*   csr_src   = (int*)  alloc((size_t)N_ * 64 * 4);
  float* XW        = (float*)alloc((size_t)N_ * 256 * 4);   // gemm output (both layers)
  float* X1        = (float*)alloc((size_t)N_ * 256 * 4);   // layer-1 activations fp32
  unsigned short* Ph  = (unsigned short*)alloc((size_t)N_ * 256 * 2);
  unsigned short* Pl  = (unsigned short*)alloc((size_t)N_ * 256 * 2);
  unsigned short* W1h = (unsigned short*)alloc(256 * 256 * 2);
  unsigned short* W1l = (unsigned short*)alloc(256 * 256 * 2);
  unsigned short* W2h = (unsigned short*)alloc(256 * 256 * 2);
  unsigned short* W2l = (unsigned short*)alloc(256 * 256 * 2);
  unsigned short* HNh = (unsigned short*)alloc((size_t)B_ * 256 * 2);
  unsigned short* HNl = (unsigned short*)alloc((size_t)B_ * 256 * 2);
  unsigned char* idxb = (unsigned char*)alloc((size_t)B_ * C_);

  hipMemsetAsync(base, 0, zero_bytes, stream);

  // prep: scatter (625) + W split (512) + zero loss/usage (79)
  k_prep<<<1216, 256, 0, stream>>>(srcp, dstp, cursor, csr_src,
                                   w1, w2, W1h, W1l, W2h, W2l, loss_out);

  dim3 ggrid(157, 8);
  k_gemm_mfma<<<ggrid, 64, 0, stream>>>(nodef, W1h, W1l, XW);
  k_agg_relu<<<N_ / 4, 256, 0, stream>>>(XW, cursor, csr_src, b1, X1);
  k_gemm_mfma<<<ggrid, 64, 0, stream>>>(X1, W2h, W2l, XW);
  k_agg_norm_split<<<N_ / 4, 256, 0, stream>>>(XW, cursor, csr_src, b2, Ph, Pl);

  // hidden normalize+split (4096 blocks) + proto colsum (100 tail blocks)
  k_norm_split<<<B_ + 100, 256, 0, stream>>>(hidden, HNh, HNl, Ph, Pl, svec);

  dim3 sgrid(125, 32);
  k_sim_max<<<sgrid, 256, 0, stream>>>(HNh, HNl, Ph, Pl, out, idxb);

  k_row_pass<<<B_ / 4, 256, 0, stream>>>(out, idxb, labels, cnt, ce_sum, pos_usage, neg_usage);
  k_finalize<<<1, 256, 0, stream>>>(svec, cnt, ce_sum, loss_out);
}